// Round 1
// baseline (558.004 us; speedup 1.0000x reference)
//
#include <hip/hip_runtime.h>
#include <cstdint>

static constexpr int M = 16384;   // B*N rows
static constexpr int D = 768;     // feature dim
static constexpr int E = 32;      // code dim
static constexpr int K = 8192;    // codebook size

// ---------------- Kernel A: H1 = tanh(X @ W1 + b1)  [M,D]x[D,D] ----------------
__global__ __launch_bounds__(256) void gemm1_tanh(
    const float* __restrict__ A, const float* __restrict__ B,
    const float* __restrict__ bias, float* __restrict__ C)
{
  constexpr int BK = 8;
  __shared__ float As[BK][128];
  __shared__ float Bs[BK][128];
  const int rowBase = blockIdx.x * 128;
  const int colBase = blockIdx.y * 128;
  const int t = threadIdx.x;
  const int tx = t & 15, ty = t >> 4;

  float acc[8][8];
#pragma unroll
  for (int i = 0; i < 8; ++i)
#pragma unroll
    for (int j = 0; j < 8; ++j) acc[i][j] = 0.f;

  const int ar = t >> 1, ak = (t & 1) * 4;   // A tile: 128 rows x 8 k
  const int bk = t >> 5, bn = (t & 31) * 4;  // B tile: 8 k x 128 n

  for (int k0 = 0; k0 < D; k0 += BK) {
    float4 av = *reinterpret_cast<const float4*>(&A[(size_t)(rowBase + ar) * D + k0 + ak]);
    float4 bv = *reinterpret_cast<const float4*>(&B[(size_t)(k0 + bk) * D + colBase + bn]);
    As[ak + 0][ar] = av.x;
    As[ak + 1][ar] = av.y;
    As[ak + 2][ar] = av.z;
    As[ak + 3][ar] = av.w;
    *reinterpret_cast<float4*>(&Bs[bk][bn]) = bv;
    __syncthreads();
#pragma unroll
    for (int kk = 0; kk < BK; ++kk) {
      float4 a0 = *reinterpret_cast<const float4*>(&As[kk][ty * 8]);
      float4 a1 = *reinterpret_cast<const float4*>(&As[kk][ty * 8 + 4]);
      float4 b0 = *reinterpret_cast<const float4*>(&Bs[kk][tx * 8]);
      float4 b1 = *reinterpret_cast<const float4*>(&Bs[kk][tx * 8 + 4]);
      float a[8] = {a0.x, a0.y, a0.z, a0.w, a1.x, a1.y, a1.z, a1.w};
      float b[8] = {b0.x, b0.y, b0.z, b0.w, b1.x, b1.y, b1.z, b1.w};
#pragma unroll
      for (int i = 0; i < 8; ++i)
#pragma unroll
        for (int j = 0; j < 8; ++j) acc[i][j] = fmaf(a[i], b[j], acc[i][j]);
    }
    __syncthreads();
  }

  float4 bv0 = *reinterpret_cast<const float4*>(&bias[colBase + tx * 8]);
  float4 bv1 = *reinterpret_cast<const float4*>(&bias[colBase + tx * 8 + 4]);
  const float bb[8] = {bv0.x, bv0.y, bv0.z, bv0.w, bv1.x, bv1.y, bv1.z, bv1.w};
#pragma unroll
  for (int i = 0; i < 8; ++i) {
    const int row = rowBase + ty * 8 + i;
    float o[8];
#pragma unroll
    for (int j = 0; j < 8; ++j) o[j] = tanhf(acc[i][j] + bb[j]);
    *reinterpret_cast<float4*>(&C[(size_t)row * D + colBase + tx * 8])     = make_float4(o[0], o[1], o[2], o[3]);
    *reinterpret_cast<float4*>(&C[(size_t)row * D + colBase + tx * 8 + 4]) = make_float4(o[4], o[5], o[6], o[7]);
  }
}

// ---------------- Kernel B: Z = l2norm(H1 @ W2 + b2)  [M,D]x[D,E] ----------------
__global__ __launch_bounds__(256) void gemm2_norm(
    const float* __restrict__ H, const float* __restrict__ W2,
    const float* __restrict__ b2, float* __restrict__ Z)
{
  __shared__ float Hs[8][D];
  const int rowBase = blockIdx.x * 8;
  const float4* src = reinterpret_cast<const float4*>(H + (size_t)rowBase * D);
  float4* dst = reinterpret_cast<float4*>(&Hs[0][0]);
  for (int i = threadIdx.x; i < 8 * D / 4; i += 256) dst[i] = src[i];
  __syncthreads();
  const int r = threadIdx.x >> 5, n = threadIdx.x & 31;
  float acc = 0.f;
#pragma unroll 8
  for (int k = 0; k < D; ++k) acc = fmaf(Hs[r][k], W2[k * E + n], acc);
  acc += b2[n];
  float ss = acc * acc;
#pragma unroll
  for (int m = 16; m >= 1; m >>= 1) ss += __shfl_xor(ss, m, 32);
  const float zv = acc / fmaxf(sqrtf(ss), 1e-12f);
  Z[(size_t)(rowBase + r) * E + n] = zv;
}

// ---------------- Kernel CC: cc[k] = sum(codebook[k]^2) ----------------
__global__ __launch_bounds__(256) void cb_norms(const float* __restrict__ CB, float* __restrict__ cc)
{
  const int k = blockIdx.x * 256 + threadIdx.x;
  const float4* p = reinterpret_cast<const float4*>(CB + (size_t)k * E);
  float s = 0.f;
#pragma unroll
  for (int q = 0; q < 8; ++q) {
    float4 v = p[q];
    s += v.x * v.x; s += v.y * v.y; s += v.z * v.z; s += v.w * v.w;
  }
  cc[k] = s;
}

// ---------------- Kernel C: argmin distance + gather + STE + per-row loss ----------------
// 32 rows / block (2 per thread), codebook staged in 512-code LDS tiles.
__global__ __launch_bounds__(256) void vq_argmin(
    const float* __restrict__ Z, const float* __restrict__ CB,
    const float* __restrict__ ccg, float* __restrict__ zq_out,
    float* __restrict__ idx_out, float* __restrict__ lossp)
{
  constexpr int CT = 512;       // codes per LDS tile
  constexpr int STRIDE = 36;    // padded floats per code (16B-aligned, conflict-light)
  __shared__ float cbs[CT * STRIDE];
  __shared__ float ccs[CT];

  const int rowBase = blockIdx.x * 32;
  const int t = threadIdx.x;
  const int cl = t & 15;        // code lane 0..15
  const int rs = t >> 4;        // row slot 0..15
  const int r0 = rowBase + rs;
  const int r1 = rowBase + rs + 16;

  float4 z0q[8], z1q[8];
  {
    const float4* p0 = reinterpret_cast<const float4*>(Z + (size_t)r0 * E);
    const float4* p1 = reinterpret_cast<const float4*>(Z + (size_t)r1 * E);
#pragma unroll
    for (int q = 0; q < 8; ++q) { z0q[q] = p0[q]; z1q[q] = p1[q]; }
  }
  float zz0 = 0.f, zz1 = 0.f;
#pragma unroll
  for (int q = 0; q < 8; ++q) {
    zz0 += z0q[q].x * z0q[q].x; zz0 += z0q[q].y * z0q[q].y;
    zz0 += z0q[q].z * z0q[q].z; zz0 += z0q[q].w * z0q[q].w;
    zz1 += z1q[q].x * z1q[q].x; zz1 += z1q[q].y * z1q[q].y;
    zz1 += z1q[q].z * z1q[q].z; zz1 += z1q[q].w * z1q[q].w;
  }

  float best0 = 3.4e38f, best1 = 3.4e38f;
  int bi0 = 0, bi1 = 0;

  for (int tb = 0; tb < K; tb += CT) {
    __syncthreads();
    const float4* src = reinterpret_cast<const float4*>(CB + (size_t)tb * E);
    for (int f = t; f < CT * 8; f += 256) {
      const int c = f >> 3, d4 = f & 7;
      *reinterpret_cast<float4*>(&cbs[c * STRIDE + d4 * 4]) = src[f];
    }
    for (int i = t; i < CT; i += 256) ccs[i] = ccg[tb + i];
    __syncthreads();

    for (int c = cl; c < CT; c += 16) {
      const float* cp = &cbs[c * STRIDE];
      float dot0 = 0.f, dot1 = 0.f;
#pragma unroll
      for (int q = 0; q < 8; ++q) {
        float4 v = *reinterpret_cast<const float4*>(cp + q * 4);
        dot0 = fmaf(v.x, z0q[q].x, dot0); dot0 = fmaf(v.y, z0q[q].y, dot0);
        dot0 = fmaf(v.z, z0q[q].z, dot0); dot0 = fmaf(v.w, z0q[q].w, dot0);
        dot1 = fmaf(v.x, z1q[q].x, dot1); dot1 = fmaf(v.y, z1q[q].y, dot1);
        dot1 = fmaf(v.z, z1q[q].z, dot1); dot1 = fmaf(v.w, z1q[q].w, dot1);
      }
      const float cv = ccs[c];
      const float d0 = (zz0 + cv) - 2.0f * dot0;
      const float d1 = (zz1 + cv) - 2.0f * dot1;
      const int kk = tb + c;
      if (d0 < best0) { best0 = d0; bi0 = kk; }
      if (d1 < best1) { best1 = d1; bi1 = kk; }
    }
  }

  // reduce over the 16 code lanes (contiguous within the wave), tie -> lowest index
#pragma unroll
  for (int m = 8; m >= 1; m >>= 1) {
    float ob = __shfl_xor(best0, m, 16);
    int   oi = __shfl_xor(bi0,   m, 16);
    if (ob < best0 || (ob == best0 && oi < bi0)) { best0 = ob; bi0 = oi; }
    ob = __shfl_xor(best1, m, 16);
    oi = __shfl_xor(bi1,   m, 16);
    if (ob < best1 || (ob == best1 && oi < bi1)) { best1 = ob; bi1 = oi; }
  }

  if (cl == 0) {
    {
      const float4* cb = reinterpret_cast<const float4*>(CB + (size_t)bi0 * E);
      float4* zo = reinterpret_cast<float4*>(zq_out + (size_t)r0 * E);
      float ls = 0.f;
#pragma unroll
      for (int q = 0; q < 8; ++q) {
        float4 c4 = cb[q];
        float4 z4 = z0q[q];
        float dx = c4.x - z4.x, dy = c4.y - z4.y, dz = c4.z - z4.z, dw = c4.w - z4.w;
        ls += dx * dx; ls += dy * dy; ls += dz * dz; ls += dw * dw;
        zo[q] = make_float4(z4.x + dx, z4.y + dy, z4.z + dz, z4.w + dw);  // STE: z + (zq - z)
      }
      idx_out[r0] = (float)bi0;
      lossp[r0] = ls;
    }
    {
      const float4* cb = reinterpret_cast<const float4*>(CB + (size_t)bi1 * E);
      float4* zo = reinterpret_cast<float4*>(zq_out + (size_t)r1 * E);
      float ls = 0.f;
#pragma unroll
      for (int q = 0; q < 8; ++q) {
        float4 c4 = cb[q];
        float4 z4 = z1q[q];
        float dx = c4.x - z4.x, dy = c4.y - z4.y, dz = c4.z - z4.z, dw = c4.w - z4.w;
        ls += dx * dx; ls += dy * dy; ls += dz * dz; ls += dw * dw;
        zo[q] = make_float4(z4.x + dx, z4.y + dy, z4.z + dz, z4.w + dw);
      }
      idx_out[r1] = (float)bi1;
      lossp[r1] = ls;
    }
  }
}

// ---------------- Kernel D: loss = sum(lossp) / (M*E) ----------------
__global__ __launch_bounds__(256) void loss_reduce(const float* __restrict__ lossp, float* __restrict__ out)
{
  float s = 0.f;
  for (int i = threadIdx.x; i < M; i += 256) s += lossp[i];
#pragma unroll
  for (int m = 32; m >= 1; m >>= 1) s += __shfl_xor(s, m, 64);
  __shared__ float red[4];
  if ((threadIdx.x & 63) == 0) red[threadIdx.x >> 6] = s;
  __syncthreads();
  if (threadIdx.x == 0)
    out[0] = (red[0] + red[1] + red[2] + red[3]) * (1.0f / (float)(M * E));
}

extern "C" void kernel_launch(void* const* d_in, const int* in_sizes, int n_in,
                              void* d_out, int out_size, void* d_ws, size_t ws_size,
                              hipStream_t stream)
{
  const float* X  = (const float*)d_in[0];  // [16,1024,768]
  const float* W1 = (const float*)d_in[1];  // [768,768]
  const float* b1 = (const float*)d_in[2];  // [768]
  const float* W2 = (const float*)d_in[3];  // [768,32]
  const float* b2 = (const float*)d_in[4];  // [32]
  const float* CB = (const float*)d_in[5];  // [8192,32]

  float* out  = (float*)d_out;
  float* zq   = out;                // 524288 floats
  float* loss = out + 524288;       // 1 float
  float* idxf = out + 524289;       // 16384 floats (indices as float)

  char* ws = (char*)d_ws;
  float* H1 = (float*)ws;                                        // M*D floats
  float* Z  = (float*)(ws + (size_t)M * D * sizeof(float));      // M*E floats
  float* cc = Z + (size_t)M * E;                                 // K floats
  float* lp = cc + K;                                            // M floats

  gemm1_tanh<<<dim3(M / 128, D / 128), 256, 0, stream>>>(X, W1, b1, H1);
  gemm2_norm<<<dim3(M / 8), 256, 0, stream>>>(H1, W2, b2, Z);
  cb_norms<<<dim3(K / 256), 256, 0, stream>>>(CB, cc);
  vq_argmin<<<dim3(M / 32), 256, 0, stream>>>(Z, CB, cc, zq, idxf, lp);
  loss_reduce<<<1, 256, 0, stream>>>(lp, loss);
}

// Round 2
// 527.555 us; speedup vs baseline: 1.0577x; 1.0577x over previous
//
#include <hip/hip_runtime.h>
#include <cstdint>

static constexpr int M = 16384;   // B*N rows
static constexpr int D = 768;     // feature dim
static constexpr int E = 32;      // code dim
static constexpr int K = 8192;    // codebook size

// ---------------- Kernel A: H1 = tanh(X @ W1 + b1)  [M,D]x[D,D] ----------------
// 128x128 tile, BK=16, reg-prefetch double buffer, swizzled Bs (2-way = free).
__global__ __launch_bounds__(256) void gemm1_tanh(
    const float* __restrict__ A, const float* __restrict__ B,
    const float* __restrict__ bias, float* __restrict__ C)
{
  constexpr int BK = 16;
  __shared__ float As[BK][128];
  __shared__ float Bs[BK][128];
  const int rowBase = blockIdx.x * 128;
  const int colBase = blockIdx.y * 128;
  const int t = threadIdx.x;
  const int tx = t & 15, ty = t >> 4;

  float acc[8][8];
#pragma unroll
  for (int i = 0; i < 8; ++i)
#pragma unroll
    for (int j = 0; j < 8; ++j) acc[i][j] = 0.f;

  // staging maps
  const int ar = t >> 1, ak = (t & 1) * 8;   // A: 128 rows x 16 k, 8 floats/thread
  const int bk = t >> 4, bn = (t & 15) * 8;  // B: 16 k x 128 n,  8 floats/thread

  // swizzle: float4-group g stored at g ^ (g>>3)  (involution, banks 2-way)
  const int gw0 = bn >> 2, gw1 = gw0 + 1;
  const int pw0 = (gw0 ^ (gw0 >> 3)) * 4, pw1 = (gw1 ^ (gw1 >> 3)) * 4;
  const int gr0 = 2 * tx, gr1 = gr0 + 1;
  const int pr0 = (gr0 ^ (gr0 >> 3)) * 4, pr1 = (gr1 ^ (gr1 >> 3)) * 4;

  const float* Aptr = A + (size_t)(rowBase + ar) * D + ak;
  const float* Bptr = B + (size_t)bk * D + colBase + bn;

  float4 a0 = *(const float4*)(Aptr);
  float4 a1 = *(const float4*)(Aptr + 4);
  float4 b0 = *(const float4*)(Bptr);
  float4 b1 = *(const float4*)(Bptr + 4);

  for (int k0 = 0; k0 < D; k0 += BK) {
    As[ak + 0][ar] = a0.x; As[ak + 1][ar] = a0.y;
    As[ak + 2][ar] = a0.z; As[ak + 3][ar] = a0.w;
    As[ak + 4][ar] = a1.x; As[ak + 5][ar] = a1.y;
    As[ak + 6][ar] = a1.z; As[ak + 7][ar] = a1.w;
    *(float4*)&Bs[bk][pw0] = b0;
    *(float4*)&Bs[bk][pw1] = b1;
    __syncthreads();
    if (k0 + BK < D) {
      const float* ap = Aptr + k0 + BK;
      const float* bp = Bptr + (size_t)(k0 + BK) * D;
      a0 = *(const float4*)ap; a1 = *(const float4*)(ap + 4);
      b0 = *(const float4*)bp; b1 = *(const float4*)(bp + 4);
    }
#pragma unroll
    for (int kk = 0; kk < BK; ++kk) {
      float4 av0 = *(const float4*)&As[kk][ty * 8];
      float4 av1 = *(const float4*)&As[kk][ty * 8 + 4];
      float4 bv0 = *(const float4*)&Bs[kk][pr0];
      float4 bv1 = *(const float4*)&Bs[kk][pr1];
      float a[8] = {av0.x, av0.y, av0.z, av0.w, av1.x, av1.y, av1.z, av1.w};
      float b[8] = {bv0.x, bv0.y, bv0.z, bv0.w, bv1.x, bv1.y, bv1.z, bv1.w};
#pragma unroll
      for (int i = 0; i < 8; ++i)
#pragma unroll
        for (int j = 0; j < 8; ++j) acc[i][j] = fmaf(a[i], b[j], acc[i][j]);
    }
    __syncthreads();
  }

  float4 bv0 = *(const float4*)&bias[colBase + tx * 8];
  float4 bv1 = *(const float4*)&bias[colBase + tx * 8 + 4];
  const float bb[8] = {bv0.x, bv0.y, bv0.z, bv0.w, bv1.x, bv1.y, bv1.z, bv1.w};
#pragma unroll
  for (int i = 0; i < 8; ++i) {
    const int row = rowBase + ty * 8 + i;
    float o[8];
#pragma unroll
    for (int j = 0; j < 8; ++j) o[j] = tanhf(acc[i][j] + bb[j]);
    *(float4*)&C[(size_t)row * D + colBase + tx * 8]     = make_float4(o[0], o[1], o[2], o[3]);
    *(float4*)&C[(size_t)row * D + colBase + tx * 8 + 4] = make_float4(o[4], o[5], o[6], o[7]);
  }
}

// ---------------- Kernel B: Z = l2norm(H1 @ W2 + b2)  [M,D]x[D,E] ----------------
// 64 rows/block; thread = (row, 8-col group); W2 chunk in LDS (broadcast reads).
__global__ __launch_bounds__(256) void gemm2_norm(
    const float* __restrict__ H, const float* __restrict__ W2,
    const float* __restrict__ b2, float* __restrict__ Z)
{
  __shared__ float Hs[64 * 132];     // 64 rows x 128 k, padded to 132
  __shared__ float W2s[128 * 32];    // k-chunk x 32
  const int t = threadIdx.x;
  const int rowBase = blockIdx.x * 64;
  const int rl = t >> 2;             // 0..63 local row
  const int n0 = (t & 3) * 8;        // col group: 0,8,16,24

  float acc[8];
#pragma unroll
  for (int j = 0; j < 8; ++j) acc[j] = 0.f;

  for (int kc = 0; kc < D; kc += 128) {
    __syncthreads();
    for (int i = t; i < 64 * 32; i += 256) {
      const int r = i >> 5, g = i & 31;
      *(float4*)&Hs[r * 132 + g * 4] =
          *(const float4*)&H[(size_t)(rowBase + r) * D + kc + g * 4];
    }
    for (int i = t; i < 128 * 8; i += 256)
      *(float4*)&W2s[i * 4] = *(const float4*)&W2[(size_t)kc * E + i * 4];
    __syncthreads();
#pragma unroll 8
    for (int k4 = 0; k4 < 32; ++k4) {
      float4 hv = *(const float4*)&Hs[rl * 132 + k4 * 4];
      const float h[4] = {hv.x, hv.y, hv.z, hv.w};
#pragma unroll
      for (int j = 0; j < 4; ++j) {
        float4 w0 = *(const float4*)&W2s[(k4 * 4 + j) * E + n0];
        float4 w1 = *(const float4*)&W2s[(k4 * 4 + j) * E + n0 + 4];
        acc[0] = fmaf(h[j], w0.x, acc[0]); acc[1] = fmaf(h[j], w0.y, acc[1]);
        acc[2] = fmaf(h[j], w0.z, acc[2]); acc[3] = fmaf(h[j], w0.w, acc[3]);
        acc[4] = fmaf(h[j], w1.x, acc[4]); acc[5] = fmaf(h[j], w1.y, acc[5]);
        acc[6] = fmaf(h[j], w1.z, acc[6]); acc[7] = fmaf(h[j], w1.w, acc[7]);
      }
    }
  }

  float4 bb0 = *(const float4*)&b2[n0];
  float4 bb1 = *(const float4*)&b2[n0 + 4];
  acc[0] += bb0.x; acc[1] += bb0.y; acc[2] += bb0.z; acc[3] += bb0.w;
  acc[4] += bb1.x; acc[5] += bb1.y; acc[6] += bb1.z; acc[7] += bb1.w;
  float ss = 0.f;
#pragma unroll
  for (int j = 0; j < 8; ++j) ss += acc[j] * acc[j];
  ss += __shfl_xor(ss, 1, 4);
  ss += __shfl_xor(ss, 2, 4);
  const float inv = 1.0f / fmaxf(sqrtf(ss), 1e-12f);
  float4 z0 = make_float4(acc[0] * inv, acc[1] * inv, acc[2] * inv, acc[3] * inv);
  float4 z1 = make_float4(acc[4] * inv, acc[5] * inv, acc[6] * inv, acc[7] * inv);
  *(float4*)&Z[(size_t)(rowBase + rl) * E + n0]     = z0;
  *(float4*)&Z[(size_t)(rowBase + rl) * E + n0 + 4] = z1;
}

// ---------------- Kernel CC: cc[k] = sum(codebook[k]^2) ----------------
__global__ __launch_bounds__(256) void cb_norms(const float* __restrict__ CB, float* __restrict__ cc)
{
  const int k = blockIdx.x * 256 + threadIdx.x;
  const float4* p = reinterpret_cast<const float4*>(CB + (size_t)k * E);
  float s = 0.f;
#pragma unroll
  for (int q = 0; q < 8; ++q) {
    float4 v = p[q];
    s += v.x * v.x; s += v.y * v.y; s += v.z * v.z; s += v.w * v.w;
  }
  cc[k] = s;
}

// ---------------- Kernel C: argmin distance + gather + STE + per-row loss ----------------
// 32 rows / block (2 per thread), codebook staged in 256-code LDS tiles (4 blocks/CU).
__global__ __launch_bounds__(256) void vq_argmin(
    const float* __restrict__ Z, const float* __restrict__ CB,
    const float* __restrict__ ccg, float* __restrict__ zq_out,
    float* __restrict__ idx_out, float* __restrict__ lossp)
{
  constexpr int CT = 256;       // codes per LDS tile
  constexpr int STRIDE = 36;    // padded floats per code
  __shared__ float cbs[CT * STRIDE];
  __shared__ float ccs[CT];

  const int rowBase = blockIdx.x * 32;
  const int t = threadIdx.x;
  const int cl = t & 15;        // code lane 0..15
  const int rs = t >> 4;        // row slot 0..15
  const int r0 = rowBase + rs;
  const int r1 = rowBase + rs + 16;

  float4 z0q[8], z1q[8];
  {
    const float4* p0 = reinterpret_cast<const float4*>(Z + (size_t)r0 * E);
    const float4* p1 = reinterpret_cast<const float4*>(Z + (size_t)r1 * E);
#pragma unroll
    for (int q = 0; q < 8; ++q) { z0q[q] = p0[q]; z1q[q] = p1[q]; }
  }
  float zz0 = 0.f, zz1 = 0.f;
#pragma unroll
  for (int q = 0; q < 8; ++q) {
    zz0 += z0q[q].x * z0q[q].x; zz0 += z0q[q].y * z0q[q].y;
    zz0 += z0q[q].z * z0q[q].z; zz0 += z0q[q].w * z0q[q].w;
    zz1 += z1q[q].x * z1q[q].x; zz1 += z1q[q].y * z1q[q].y;
    zz1 += z1q[q].z * z1q[q].z; zz1 += z1q[q].w * z1q[q].w;
  }

  float best0 = 3.4e38f, best1 = 3.4e38f;
  int bi0 = 0, bi1 = 0;

  for (int tb = 0; tb < K; tb += CT) {
    __syncthreads();
    const float4* src = reinterpret_cast<const float4*>(CB + (size_t)tb * E);
    for (int f = t; f < CT * 8; f += 256) {
      const int c = f >> 3, d4 = f & 7;
      *reinterpret_cast<float4*>(&cbs[c * STRIDE + d4 * 4]) = src[f];
    }
    if (t < CT) ccs[t] = ccg[tb + t];
    __syncthreads();

    for (int c = cl; c < CT; c += 16) {
      const float* cp = &cbs[c * STRIDE];
      float dot0 = 0.f, dot1 = 0.f;
#pragma unroll
      for (int q = 0; q < 8; ++q) {
        float4 v = *reinterpret_cast<const float4*>(cp + q * 4);
        dot0 = fmaf(v.x, z0q[q].x, dot0); dot0 = fmaf(v.y, z0q[q].y, dot0);
        dot0 = fmaf(v.z, z0q[q].z, dot0); dot0 = fmaf(v.w, z0q[q].w, dot0);
        dot1 = fmaf(v.x, z1q[q].x, dot1); dot1 = fmaf(v.y, z1q[q].y, dot1);
        dot1 = fmaf(v.z, z1q[q].z, dot1); dot1 = fmaf(v.w, z1q[q].w, dot1);
      }
      const float cv = ccs[c];
      const float d0 = (zz0 + cv) - 2.0f * dot0;
      const float d1 = (zz1 + cv) - 2.0f * dot1;
      const int kk = tb + c;
      if (d0 < best0) { best0 = d0; bi0 = kk; }
      if (d1 < best1) { best1 = d1; bi1 = kk; }
    }
  }

#pragma unroll
  for (int m = 8; m >= 1; m >>= 1) {
    float ob = __shfl_xor(best0, m, 16);
    int   oi = __shfl_xor(bi0,   m, 16);
    if (ob < best0 || (ob == best0 && oi < bi0)) { best0 = ob; bi0 = oi; }
    ob = __shfl_xor(best1, m, 16);
    oi = __shfl_xor(bi1,   m, 16);
    if (ob < best1 || (ob == best1 && oi < bi1)) { best1 = ob; bi1 = oi; }
  }

  if (cl == 0) {
    {
      const float4* cb = reinterpret_cast<const float4*>(CB + (size_t)bi0 * E);
      float4* zo = reinterpret_cast<float4*>(zq_out + (size_t)r0 * E);
      float ls = 0.f;
#pragma unroll
      for (int q = 0; q < 8; ++q) {
        float4 c4 = cb[q];
        float4 z4 = z0q[q];
        float dx = c4.x - z4.x, dy = c4.y - z4.y, dz = c4.z - z4.z, dw = c4.w - z4.w;
        ls += dx * dx; ls += dy * dy; ls += dz * dz; ls += dw * dw;
        zo[q] = make_float4(z4.x + dx, z4.y + dy, z4.z + dz, z4.w + dw);  // STE
      }
      idx_out[r0] = (float)bi0;
      lossp[r0] = ls;
    }
    {
      const float4* cb = reinterpret_cast<const float4*>(CB + (size_t)bi1 * E);
      float4* zo = reinterpret_cast<float4*>(zq_out + (size_t)r1 * E);
      float ls = 0.f;
#pragma unroll
      for (int q = 0; q < 8; ++q) {
        float4 c4 = cb[q];
        float4 z4 = z1q[q];
        float dx = c4.x - z4.x, dy = c4.y - z4.y, dz = c4.z - z4.z, dw = c4.w - z4.w;
        ls += dx * dx; ls += dy * dy; ls += dz * dz; ls += dw * dw;
        zo[q] = make_float4(z4.x + dx, z4.y + dy, z4.z + dz, z4.w + dw);
      }
      idx_out[r1] = (float)bi1;
      lossp[r1] = ls;
    }
  }
}

// ---------------- Kernel D: loss = sum(lossp) / (M*E) ----------------
__global__ __launch_bounds__(256) void loss_reduce(const float* __restrict__ lossp, float* __restrict__ out)
{
  float s = 0.f;
  const float4* p = reinterpret_cast<const float4*>(lossp);
  for (int i = threadIdx.x; i < M / 4; i += 256) {
    float4 v = p[i];
    s += v.x + v.y + v.z + v.w;
  }
#pragma unroll
  for (int m = 32; m >= 1; m >>= 1) s += __shfl_xor(s, m, 64);
  __shared__ float red[4];
  if ((threadIdx.x & 63) == 0) red[threadIdx.x >> 6] = s;
  __syncthreads();
  if (threadIdx.x == 0)
    out[0] = (red[0] + red[1] + red[2] + red[3]) * (1.0f / (float)(M * E));
}

extern "C" void kernel_launch(void* const* d_in, const int* in_sizes, int n_in,
                              void* d_out, int out_size, void* d_ws, size_t ws_size,
                              hipStream_t stream)
{
  const float* X  = (const float*)d_in[0];  // [16,1024,768]
  const float* W1 = (const float*)d_in[1];  // [768,768]
  const float* b1 = (const float*)d_in[2];  // [768]
  const float* W2 = (const float*)d_in[3];  // [768,32]
  const float* b2 = (const float*)d_in[4];  // [32]
  const float* CB = (const float*)d_in[5];  // [8192,32]

  float* out  = (float*)d_out;
  float* zq   = out;                // 524288 floats
  float* loss = out + 524288;       // 1 float
  float* idxf = out + 524289;       // 16384 floats

  char* ws = (char*)d_ws;
  float* H1 = (float*)ws;                                        // M*D floats
  float* Z  = (float*)(ws + (size_t)M * D * sizeof(float));      // M*E floats
  float* cc = Z + (size_t)M * E;                                 // K floats
  float* lp = cc + K;                                            // M floats

  gemm1_tanh<<<dim3(M / 128, D / 128), 256, 0, stream>>>(X, W1, b1, H1);
  gemm2_norm<<<dim3(M / 64), 256, 0, stream>>>(H1, W2, b2, Z);
  cb_norms<<<dim3(K / 256), 256, 0, stream>>>(CB, cc);
  vq_argmin<<<dim3(M / 32), 256, 0, stream>>>(Z, CB, cc, zq, idxf, lp);
  loss_reduce<<<1, 256, 0, stream>>>(lp, loss);
}